// Round 10
// baseline (220.138 us; speedup 1.0000x reference)
//
#include <hip/hip_runtime.h>

#define HW 256
#define HWHW 65536
#define TOTAL 19296

typedef __attribute__((ext_vector_type(8))) short short8;
typedef __attribute__((ext_vector_type(4))) float float4v;

__device__ inline unsigned bfr(float f) {  // bf16 bits (round half-up), low 16
    return (__builtin_bit_cast(unsigned, f) + 0x8000u) >> 16;
}
__device__ inline unsigned pack2rnd(float lo, float hi) {  // [bf(hi):bf(lo)] via v_perm
    unsigned a = __builtin_bit_cast(unsigned, lo) + 0x8000u;
    unsigned b = __builtin_bit_cast(unsigned, hi) + 0x8000u;
    return __builtin_amdgcn_perm(b, a, 0x07060302u);
}

// ---------------- MLP: grid (2 j-halves, 16 b); layer1 recomputed per block ----------------
__global__ __launch_bounds__(256) void mlp_kernel(
    const float* __restrict__ x_meta, const float* __restrict__ w0, const float* __restrict__ b0,
    const float* __restrict__ w1, const float* __restrict__ b1, float* __restrict__ h1)
{
    int b = blockIdx.y, jh = blockIdx.x, t = threadIdx.x;
    __shared__ float xm[16];
    __shared__ float h0s[256];
    if (t < 16) xm[t] = x_meta[b * 16 + t];
    __syncthreads();
    {
        float a0 = b0[t];
#pragma unroll
        for (int i = 0; i < 16; ++i) a0 += xm[i] * w0[i * 256 + t];
        h0s[t] = fmaxf(a0, 0.f);
    }
    __syncthreads();
    int j = jh * 256 + t;
    float acc = b1[j];
#pragma unroll 4
    for (int k = 0; k < 256; ++k) acc += h0s[k] * w1[k * 512 + j];
    h1[b * 512 + j] = fmaxf(acc, 0.f);
}

// ---------------- flat: full-K GEMM + bias + relu + scatter. grid (302) ----------------
__global__ __launch_bounds__(256) void flat_kernel(
    const float* __restrict__ h1, const float* __restrict__ w2, const float* __restrict__ b2,
    float* __restrict__ wc0, unsigned short* __restrict__ wc1, unsigned short* __restrict__ wc2)
{
    __shared__ float h1s[16 * 512];
    int t = threadIdx.x;
    for (int i = t; i < 2048; i += 256) ((float4*)h1s)[i] = ((const float4*)h1)[i];
    __syncthreads();
    int j = blockIdx.x * 64 + (t & 63);
    if (j >= TOTAL) j = TOTAL - 1;  // dup threads write same value: benign
    int bq = t >> 6;                // 0..3
    const float* wp = w2 + j;
    float a0 = 0.f, a1 = 0.f, a2 = 0.f, a3 = 0.f;
    for (int k = 0; k < 512; k += 4) {
        float wv0 = wp[(size_t)(k + 0) * TOTAL];
        float wv1 = wp[(size_t)(k + 1) * TOTAL];
        float wv2 = wp[(size_t)(k + 2) * TOTAL];
        float wv3 = wp[(size_t)(k + 3) * TOTAL];
        const float4 h0v = *(const float4*)&h1s[(bq * 4 + 0) * 512 + k];
        const float4 h1v = *(const float4*)&h1s[(bq * 4 + 1) * 512 + k];
        const float4 h2v = *(const float4*)&h1s[(bq * 4 + 2) * 512 + k];
        const float4 h3v = *(const float4*)&h1s[(bq * 4 + 3) * 512 + k];
        a0 += h0v.x * wv0 + h0v.y * wv1 + h0v.z * wv2 + h0v.w * wv3;
        a1 += h1v.x * wv0 + h1v.y * wv1 + h1v.z * wv2 + h1v.w * wv3;
        a2 += h2v.x * wv0 + h2v.y * wv1 + h2v.z * wv2 + h2v.w * wv3;
        a3 += h3v.x * wv0 + h3v.y * wv1 + h3v.z * wv2 + h3v.w * wv3;
    }
    float bj = b2[j];
    float vq[4] = {a0, a1, a2, a3};
#pragma unroll
    for (int q = 0; q < 4; ++q) {
        int b = bq * 4 + q;
        float v = fmaxf(vq[q] + bj, 0.f);
        if (j < 288) {
            wc0[b * 288 + j] = v;
        } else if (j < 18720) {
            int r = j - 288;
            int oc = r / 288; int rem = r - oc * 288;
            int ic = rem / 9;  int tap = rem - ic * 9;
            wc1[(((b * 9 + tap) * 64 + oc) << 5) + ic] = (unsigned short)bfr(v);
        } else {
            int r = j - 18720;
            int ic = r / 9; int tap = r - ic * 9;
            wc2[(b * 9 + tap) * 64 + ic] = (unsigned short)bfr(v);
        }
    }
}

// ---------------- fused conv0+conv1+conv2: one 16x16 output tile per 512-thread block ----------------
// __launch_bounds__(512,4): VGPR cap 128 (kernel needs ~116 incl unified AGPRs; (512,6) spills — r8).
// LDS 58368 B -> 2 blocks/CU:
//   phase A: b0s [400 px][32 sh, 64 B stride, XOR 16B groups g^((px>>1)&3)] @0      (25600 B)
//            xtb [400 px][24 sh, 48 B stride] im2col conv0-B (taps 0..8, rest 0) @25600 (19200 B)
//   phase B: b1s [324 px][64 sh, 128 B stride, XOR 16B groups g^(px&7)] @0          (41472 B)
//            pbuf [324][13] f32 @41472 (16848 B; overlaps only dead xtb tail)
// xtb holds ZEROS for out-of-image px -> conv0 output auto-zero (no vis masking in conv0).
__global__ __launch_bounds__(512, 4) void fused_conv_kernel(
    const float* __restrict__ x, const float* __restrict__ wc0,
    const unsigned short* __restrict__ wc1, const unsigned short* __restrict__ wc2,
    float* __restrict__ out)
{
    __shared__ __align__(16) char smem[58368];
    short* b0s  = (short*)smem;
    short* xtb  = (short*)(smem + 25600);
    short* b1s  = (short*)smem;
    float* pbuf = (float*)(smem + 41472);

    const int t = threadIdx.x;
    const int bx = blockIdx.x, b = blockIdx.y;
    const int x0 = (bx & 15) << 4, y0 = (bx >> 4) << 4;
    const int lane = t & 63, wave = t >> 6;
    const int l15 = lane & 15, lg = lane >> 4;
    const float* xb = x + (size_t)b * HWHW;

    // ---- A-fragment global loads first (latency overlapped with xtb build) ----
    // conv0 A: M=32 oc, K=taps(9, pad 32) from wc0
    short8 A0, A1;
    {
        short8 z = {0,0,0,0,0,0,0,0};
        A0 = z; A1 = z;
        const float* wbase = wc0 + b * 288;
#pragma unroll
        for (int mt = 0; mt < 2; ++mt) {
            const float* wp = wbase + (mt * 16 + l15) * 9;
            short8 a = z;
            if (lg == 0) {
                uint4 pk;
                pk.x = pack2rnd(wp[0], wp[1]);
                pk.y = pack2rnd(wp[2], wp[3]);
                pk.z = pack2rnd(wp[4], wp[5]);
                pk.w = pack2rnd(wp[6], wp[7]);
                a = __builtin_bit_cast(short8, pk);
            } else if (lg == 1) {
                a[0] = (short)bfr(wp[8]);
            }
            if (mt == 0) A0 = a; else A1 = a;
        }
    }
    // conv1 tap-0 A prefetch
    const unsigned short* wb = wc1 + (size_t)b * 18432;  // [tap][oc64][ic32]
    short8 Apre[4];
#pragma unroll
    for (int mt = 0; mt < 4; ++mt)
        Apre[mt] = *(const short8*)(wb + (mt * 16 + l15) * 32 + lg * 8);
    // conv2 A: A[m=tap][k=oc], rows 9..15 zero
    short8 A2[2];
#pragma unroll
    for (int kc = 0; kc < 2; ++kc) {
        int tp = l15 < 9 ? l15 : 0;
        short8 v = *(const short8*)(wc2 + b * 576 + tp * 64 + kc * 32 + lg * 8);
        short8 z = {0, 0, 0, 0, 0, 0, 0, 0};
        A2[kc] = (l15 < 9) ? v : z;
    }

    // ---- xtb im2col build: 400 px (20x20 halo), 9 bf16 taps + zero pad; zeros if px OOB ----
    if (t < 400) {
        int r0 = t / 20, c0 = t - r0 * 20;
        int gy = y0 - 2 + r0, gx = x0 - 2 + c0;
        bool vis = ((unsigned)gy < (unsigned)HW) && ((unsigned)gx < (unsigned)HW);
        int cy[3], cxv[3]; bool oy[3], ox[3];
#pragma unroll
        for (int d = 0; d < 3; ++d) {
            int Y = gy - 1 + d; oy[d] = ((unsigned)Y < (unsigned)HW); cy[d] = oy[d] ? Y : 0;
            int X = gx - 1 + d; ox[d] = ((unsigned)X < (unsigned)HW); cxv[d] = ox[d] ? X : 0;
        }
        float v[9];
#pragma unroll
        for (int k = 0; k < 9; ++k) {
            int ky = k / 3, kx = k - ky * 3;
            float lv = xb[cy[ky] * HW + cxv[kx]];
            v[k] = (vis && oy[ky] && ox[kx]) ? lv : 0.f;
        }
        uint4 q0, q1;
        q0.x = pack2rnd(v[0], v[1]); q0.y = pack2rnd(v[2], v[3]);
        q0.z = pack2rnd(v[4], v[5]); q0.w = pack2rnd(v[6], v[7]);
        q1.x = pack2rnd(v[8], 0.f);  q1.y = 0; q1.z = 0; q1.w = 0;
        char* d = (char*)xtb + t * 48;
        *(uint4*)d = q0;
        *(uint4*)(d + 16) = q1;
    }
    __syncthreads();   // 1

    // ---- conv0 via MFMA: N=400 px in 25 groups over 8 waves; B from xtb (zero-padded) ----
    for (int g = wave; g < 25; g += 8) {
        int px = g * 16 + l15;                 // 0..399
        short8 Bf = {0,0,0,0,0,0,0,0};
        if (lg < 2) Bf = *(const short8*)((const char*)xtb + px * 48 + lg * 16);
        float4v zz = {0.f, 0.f, 0.f, 0.f};
        float4v d0 = __builtin_amdgcn_mfma_f32_16x16x32_bf16(A0, Bf, zz, 0, 0, 0);
        float4v d1 = __builtin_amdgcn_mfma_f32_16x16x32_bf16(A1, Bf, zz, 0, 0, 0);
        uint2 wv0, wv1;
        wv0.x = pack2rnd(d0[0], d0[1]); wv0.y = pack2rnd(d0[2], d0[3]);
        wv1.x = pack2rnd(d1[0], d1[1]); wv1.y = pack2rnd(d1[2], d1[3]);
        // b0s write: chunk c = lg (wv0) / 4+lg (wv1); group = c>>1 ^ ((px>>1)&3); inner = lg&1
        int psw = (px >> 1) & 3;
        char* base = (char*)b0s + px * 64 + ((lg & 1) << 3);
        *(uint2*)(base + ((((lg >> 1)    ) ^ psw) << 4)) = wv0;
        *(uint2*)(base + ((((lg >> 1) + 2) ^ psw) << 4)) = wv1;
    }
    __syncthreads();   // 2

    // ---- conv1: 21 groups of 16 px over 18x18; 3 slots per wave; A software-pipelined ----
    int  p2c[3];
    int  pxb[3];   // b0s px index (20x20 domain) for tap 0
    bool inb[3];
#pragma unroll
    for (int i = 0; i < 3; ++i) {
        int g = wave + i * 8;
        if (g < 21) {
            int p2 = g * 16 + l15;
            int pc = p2 > 323 ? 323 : p2;
            p2c[i] = pc;
            int r2 = pc / 18, c2 = pc - r2 * 18;
            pxb[i] = r2 * 20 + c2;
            int gy1 = y0 - 1 + r2, gx1 = x0 - 1 + c2;
            inb[i] = (gy1 >= 0 && gy1 < HW && gx1 >= 0 && gx1 < HW);
        }
    }
    float4v acc1[3][4];
#pragma unroll
    for (int i = 0; i < 3; ++i)
#pragma unroll
        for (int mt = 0; mt < 4; ++mt) acc1[i][mt] = (float4v){0.f, 0.f, 0.f, 0.f};

#pragma unroll
    for (int tap = 0; tap < 9; ++tap) {
        const int ky = tap / 3, kx = tap - (tap / 3) * 3;
        const int po = ky * 20 + kx;
        short8 A[4];
#pragma unroll
        for (int mt = 0; mt < 4; ++mt) A[mt] = Apre[mt];
        if (tap < 8) {
#pragma unroll
            for (int mt = 0; mt < 4; ++mt)
                Apre[mt] = *(const short8*)(wb + (tap + 1) * 2048 + (mt * 16 + l15) * 32 + lg * 8);
        }
#pragma unroll
        for (int i = 0; i < 3; ++i) {
            int g = wave + i * 8;
            if (g < 21) {
                int px20 = pxb[i] + po;
                short8 Bf = *(const short8*)((const char*)b0s + px20 * 64 +
                                             ((lg ^ ((px20 >> 1) & 3)) << 4));
#pragma unroll
                for (int mt = 0; mt < 4; ++mt)
                    acc1[i][mt] = __builtin_amdgcn_mfma_f32_16x16x32_bf16(A[mt], Bf, acc1[i][mt], 0, 0, 0);
            }
        }
    }
    __syncthreads();   // 3 — all b0s/xtb reads done; b1s may overlay

    // ---- conv1 C -> b1s (bf16, swizzled), zeroing out-of-image px ----
#pragma unroll
    for (int i = 0; i < 3; ++i) {
        int g = wave + i * 8;
        if (g < 21) {
            int pc = p2c[i];
            int psw = pc & 7;
#pragma unroll
            for (int mt = 0; mt < 4; ++mt) {
                unsigned lo = pack2rnd(acc1[i][mt][0], acc1[i][mt][1]);
                unsigned hi = pack2rnd(acc1[i][mt][2], acc1[i][mt][3]);
                if (!inb[i]) { lo = 0; hi = 0; }
                uint2 pk; pk.x = lo; pk.y = hi;
                *(uint2*)((char*)b1s + pc * 128 +
                          ((((mt * 2 + (lg >> 1)) ^ psw)) << 4) + ((lg & 1) << 3)) = pk;
            }
        }
    }
    __syncthreads();   // 4

    // ---- conv2: C[m=tap][n=px] over 18x18; B from b1s; write pbuf immediately (own region) ----
#pragma unroll
    for (int i = 0; i < 3; ++i) {
        int g = wave + i * 8;
        if (g < 21) {
            int pc = p2c[i];
            int psw = pc & 7;
            float4v acc2 = (float4v){0.f, 0.f, 0.f, 0.f};
#pragma unroll
            for (int kc = 0; kc < 2; ++kc) {
                short8 Bf = *(const short8*)((const char*)b1s + pc * 128 +
                                             (((kc * 4 + lg) ^ psw) << 4));
                acc2 = __builtin_amdgcn_mfma_f32_16x16x32_bf16(A2[kc], Bf, acc2, 0, 0, 0);
            }
            if (lg < 2) {
#pragma unroll
                for (int u = 0; u < 4; ++u) pbuf[pc * 13 + lg * 4 + u] = acc2[u];
            } else if (lg == 2) {
                pbuf[pc * 13 + 8] = acc2[0];
            }
        }
    }
    __syncthreads();   // 5

    // ---- reduction: out(r,c) = sum_tap pbuf[(r+ky)*18 + (c+kx)][tap] ----
    if (t < 256) {
        int r = t >> 4, c = t & 15;
        float o = 0.f;
#pragma unroll
        for (int ky = 0; ky < 3; ++ky)
#pragma unroll
            for (int kx = 0; kx < 3; ++kx)
                o += pbuf[((r + ky) * 18 + (c + kx)) * 13 + (ky * 3 + kx)];
        out[(size_t)b * HWHW + (y0 + r) * HW + (x0 + c)] = o;
    }
}

extern "C" void kernel_launch(void* const* d_in, const int* in_sizes, int n_in,
                              void* d_out, int out_size, void* d_ws, size_t ws_size,
                              hipStream_t stream)
{
    const float* x_meta = (const float*)d_in[0];
    const float* x      = (const float*)d_in[1];
    const float* w0     = (const float*)d_in[2];
    const float* b0     = (const float*)d_in[3];
    const float* w1     = (const float*)d_in[4];
    const float* b1     = (const float*)d_in[5];
    const float* w2     = (const float*)d_in[6];
    const float* b2     = (const float*)d_in[7];
    float* out = (float*)d_out;

    char* ws = (char*)d_ws;
    float* h1 = (float*)ws;                                                // @0       32768 B
    float* wc0 = (float*)(ws + 32768);                                     // @32768   18432 B
    unsigned short* wc1 = (unsigned short*)(ws + 51200);                   // @51200   589824 B
    unsigned short* wc2 = (unsigned short*)(ws + 641024);                  // @641024  18432 B

    mlp_kernel<<<dim3(2, 16), 256, 0, stream>>>(x_meta, w0, b0, w1, b1, h1);
    flat_kernel<<<302, 256, 0, stream>>>(h1, w2, b2, wc0, wc1, wc2);
    fused_conv_kernel<<<dim3(256, 16), 512, 0, stream>>>(x, wc0, wc1, wc2, out);
}

// Round 11
// 215.509 us; speedup vs baseline: 1.0215x; 1.0215x over previous
//
#include <hip/hip_runtime.h>

#define HW 256
#define HWHW 65536
#define TOTAL 19296

typedef __attribute__((ext_vector_type(8))) short short8;
typedef __attribute__((ext_vector_type(4))) float float4v;

__device__ inline unsigned bfr(float f) {  // bf16 bits (round half-up), low 16
    return (__builtin_bit_cast(unsigned, f) + 0x8000u) >> 16;
}
__device__ inline unsigned pack2rnd(float lo, float hi) {  // [bf(hi):bf(lo)] via v_perm
    unsigned a = __builtin_bit_cast(unsigned, lo) + 0x8000u;
    unsigned b = __builtin_bit_cast(unsigned, hi) + 0x8000u;
    return __builtin_amdgcn_perm(b, a, 0x07060302u);
}

// ---------------- MLP: grid (2 j-halves, 16 b); layer1 recomputed per block ----------------
__global__ __launch_bounds__(256) void mlp_kernel(
    const float* __restrict__ x_meta, const float* __restrict__ w0, const float* __restrict__ b0,
    const float* __restrict__ w1, const float* __restrict__ b1, float* __restrict__ h1)
{
    int b = blockIdx.y, jh = blockIdx.x, t = threadIdx.x;
    __shared__ float xm[16];
    __shared__ float h0s[256];
    if (t < 16) xm[t] = x_meta[b * 16 + t];
    __syncthreads();
    {
        float a0 = b0[t];
#pragma unroll
        for (int i = 0; i < 16; ++i) a0 += xm[i] * w0[i * 256 + t];
        h0s[t] = fmaxf(a0, 0.f);
    }
    __syncthreads();
    int j = jh * 256 + t;
    float acc = b1[j];
#pragma unroll 4
    for (int k = 0; k < 256; ++k) acc += h0s[k] * w1[k * 512 + j];
    h1[b * 512 + j] = fmaxf(acc, 0.f);
}

// ---------------- flat: full-K GEMM + bias + relu + scatter. grid (302) ----------------
// wc2 is written in conv2's PERMUTED k-order so the fused kernel can consume conv1's
// C registers directly as conv2's B operand (no LDS transpose):
//   ic = mt*16 + lgp*4 + reg  ->  kperm = (mt>>1)*32 + lgp*8 + (mt&1)*4 + reg
__global__ __launch_bounds__(256) void flat_kernel(
    const float* __restrict__ h1, const float* __restrict__ w2, const float* __restrict__ b2,
    float* __restrict__ wc0, unsigned short* __restrict__ wc1, unsigned short* __restrict__ wc2)
{
    __shared__ float h1s[16 * 512];
    int t = threadIdx.x;
    for (int i = t; i < 2048; i += 256) ((float4*)h1s)[i] = ((const float4*)h1)[i];
    __syncthreads();
    int j = blockIdx.x * 64 + (t & 63);
    if (j >= TOTAL) j = TOTAL - 1;  // dup threads write same value: benign
    int bq = t >> 6;                // 0..3
    const float* wp = w2 + j;
    float a0 = 0.f, a1 = 0.f, a2 = 0.f, a3 = 0.f;
    for (int k = 0; k < 512; k += 4) {
        float wv0 = wp[(size_t)(k + 0) * TOTAL];
        float wv1 = wp[(size_t)(k + 1) * TOTAL];
        float wv2 = wp[(size_t)(k + 2) * TOTAL];
        float wv3 = wp[(size_t)(k + 3) * TOTAL];
        const float4 h0v = *(const float4*)&h1s[(bq * 4 + 0) * 512 + k];
        const float4 h1v = *(const float4*)&h1s[(bq * 4 + 1) * 512 + k];
        const float4 h2v = *(const float4*)&h1s[(bq * 4 + 2) * 512 + k];
        const float4 h3v = *(const float4*)&h1s[(bq * 4 + 3) * 512 + k];
        a0 += h0v.x * wv0 + h0v.y * wv1 + h0v.z * wv2 + h0v.w * wv3;
        a1 += h1v.x * wv0 + h1v.y * wv1 + h1v.z * wv2 + h1v.w * wv3;
        a2 += h2v.x * wv0 + h2v.y * wv1 + h2v.z * wv2 + h2v.w * wv3;
        a3 += h3v.x * wv0 + h3v.y * wv1 + h3v.z * wv2 + h3v.w * wv3;
    }
    float bj = b2[j];
    float vq[4] = {a0, a1, a2, a3};
#pragma unroll
    for (int q = 0; q < 4; ++q) {
        int b = bq * 4 + q;
        float v = fmaxf(vq[q] + bj, 0.f);
        if (j < 288) {
            wc0[b * 288 + j] = v;
        } else if (j < 18720) {
            int r = j - 288;
            int oc = r / 288; int rem = r - oc * 288;
            int ic = rem / 9;  int tap = rem - ic * 9;
            wc1[(((b * 9 + tap) * 64 + oc) << 5) + ic] = (unsigned short)bfr(v);
        } else {
            int r = j - 18720;
            int ic = r / 9; int tap = r - ic * 9;
            int mt = ic >> 4, lgp = (ic >> 2) & 3, reg = ic & 3;
            int kperm = ((mt >> 1) << 5) + (lgp << 3) + ((mt & 1) << 2) + reg;
            wc2[(b * 9 + tap) * 64 + kperm] = (unsigned short)bfr(v);
        }
    }
}

// ---------------- fused conv0+conv1+conv2: one 16x16 output tile per 512-thread block ----------------
// __launch_bounds__(512,4): VGPR cap 128 ((512,6) spills catastrophically — r8 post-mortem).
// LDS 61648 B -> 2 blocks/CU, THREE barriers total:
//   b0s  [400 px][32 sh, 64 B stride, XOR 16B groups g^((px>>1)&3)] @0      (25600 B)
//   xtb  [400 px][24 sh, 48 B stride] im2col conv0-B (taps 0..8, pad 0) @25600 (19200 B)
//   pbuf [324][13] f32 @44800 (16848 B, own region)
// conv1 C feeds conv2 B DIRECTLY from registers: conv2's k-order is permuted (see flat_kernel)
// so B-frag[kc] = pack_bf16(acc1[2kc][0..3], acc1[2kc+1][0..3]) — no LDS transpose, no b1s.
__global__ __launch_bounds__(512, 4) void fused_conv_kernel(
    const float* __restrict__ x, const float* __restrict__ wc0,
    const unsigned short* __restrict__ wc1, const unsigned short* __restrict__ wc2,
    float* __restrict__ out)
{
    __shared__ __align__(16) char smem[61648];
    short* b0s  = (short*)smem;
    short* xtb  = (short*)(smem + 25600);
    float* pbuf = (float*)(smem + 44800);

    const int t = threadIdx.x;
    const int bx = blockIdx.x, b = blockIdx.y;
    const int x0 = (bx & 15) << 4, y0 = (bx >> 4) << 4;
    const int lane = t & 63, wave = t >> 6;
    const int l15 = lane & 15, lg = lane >> 4;
    const float* xb = x + (size_t)b * HWHW;

    // ---- A-fragment global loads first (latency overlapped with xtb build) ----
    short8 A0, A1;
    {
        short8 z = {0,0,0,0,0,0,0,0};
        A0 = z; A1 = z;
        const float* wbase = wc0 + b * 288;
#pragma unroll
        for (int mt = 0; mt < 2; ++mt) {
            const float* wp = wbase + (mt * 16 + l15) * 9;
            short8 a = z;
            if (lg == 0) {
                uint4 pk;
                pk.x = pack2rnd(wp[0], wp[1]);
                pk.y = pack2rnd(wp[2], wp[3]);
                pk.z = pack2rnd(wp[4], wp[5]);
                pk.w = pack2rnd(wp[6], wp[7]);
                a = __builtin_bit_cast(short8, pk);
            } else if (lg == 1) {
                a[0] = (short)bfr(wp[8]);
            }
            if (mt == 0) A0 = a; else A1 = a;
        }
    }
    // conv1 tap-0 A prefetch
    const unsigned short* wb = wc1 + (size_t)b * 18432;  // [tap][oc64][ic32]
    short8 Apre[4];
#pragma unroll
    for (int mt = 0; mt < 4; ++mt)
        Apre[mt] = *(const short8*)(wb + (mt * 16 + l15) * 32 + lg * 8);
    // conv2 A (permuted k-order, contiguous): A[m=tap][k], rows 9..15 zero
    short8 A2[2];
#pragma unroll
    for (int kc = 0; kc < 2; ++kc) {
        int tp = l15 < 9 ? l15 : 0;
        short8 v = *(const short8*)(wc2 + b * 576 + tp * 64 + kc * 32 + lg * 8);
        short8 z = {0, 0, 0, 0, 0, 0, 0, 0};
        A2[kc] = (l15 < 9) ? v : z;
    }

    // ---- xtb im2col build: 400 px (20x20 halo), 9 bf16 taps + zero pad; zeros if px OOB ----
    if (t < 400) {
        int r0 = t / 20, c0 = t - r0 * 20;
        int gy = y0 - 2 + r0, gx = x0 - 2 + c0;
        bool vis = ((unsigned)gy < (unsigned)HW) && ((unsigned)gx < (unsigned)HW);
        int cy[3], cxv[3]; bool oy[3], ox[3];
#pragma unroll
        for (int d = 0; d < 3; ++d) {
            int Y = gy - 1 + d; oy[d] = ((unsigned)Y < (unsigned)HW); cy[d] = oy[d] ? Y : 0;
            int X = gx - 1 + d; ox[d] = ((unsigned)X < (unsigned)HW); cxv[d] = ox[d] ? X : 0;
        }
        float v[9];
#pragma unroll
        for (int k = 0; k < 9; ++k) {
            int ky = k / 3, kx = k - ky * 3;
            float lv = xb[cy[ky] * HW + cxv[kx]];
            v[k] = (vis && oy[ky] && ox[kx]) ? lv : 0.f;
        }
        uint4 q0, q1;
        q0.x = pack2rnd(v[0], v[1]); q0.y = pack2rnd(v[2], v[3]);
        q0.z = pack2rnd(v[4], v[5]); q0.w = pack2rnd(v[6], v[7]);
        q1.x = pack2rnd(v[8], 0.f);  q1.y = 0; q1.z = 0; q1.w = 0;
        char* d = (char*)xtb + t * 48;
        *(uint4*)d = q0;
        *(uint4*)(d + 16) = q1;
    }
    __syncthreads();   // 1

    // ---- conv0 via MFMA: N=400 px in 25 groups over 8 waves; B from xtb (zero-padded) ----
    for (int g = wave; g < 25; g += 8) {
        int px = g * 16 + l15;                 // 0..399
        short8 Bf = {0,0,0,0,0,0,0,0};
        if (lg < 2) Bf = *(const short8*)((const char*)xtb + px * 48 + lg * 16);
        float4v zz = {0.f, 0.f, 0.f, 0.f};
        float4v d0 = __builtin_amdgcn_mfma_f32_16x16x32_bf16(A0, Bf, zz, 0, 0, 0);
        float4v d1 = __builtin_amdgcn_mfma_f32_16x16x32_bf16(A1, Bf, zz, 0, 0, 0);
        uint2 wv0, wv1;
        wv0.x = pack2rnd(d0[0], d0[1]); wv0.y = pack2rnd(d0[2], d0[3]);
        wv1.x = pack2rnd(d1[0], d1[1]); wv1.y = pack2rnd(d1[2], d1[3]);
        // b0s write: chunk c = lg (wv0) / 4+lg (wv1); group = c>>1 ^ ((px>>1)&3); inner = lg&1
        int psw = (px >> 1) & 3;
        char* base = (char*)b0s + px * 64 + ((lg & 1) << 3);
        *(uint2*)(base + ((((lg >> 1)    ) ^ psw) << 4)) = wv0;
        *(uint2*)(base + ((((lg >> 1) + 2) ^ psw) << 4)) = wv1;
    }
    __syncthreads();   // 2

    // ---- conv1: 21 groups of 16 px over 18x18; 3 slots per wave; A software-pipelined ----
    int  p2c[3];
    int  pxb[3];   // b0s px index (20x20 domain) for tap 0
    bool inb[3];
#pragma unroll
    for (int i = 0; i < 3; ++i) {
        int g = wave + i * 8;
        if (g < 21) {
            int p2 = g * 16 + l15;
            int pc = p2 > 323 ? 323 : p2;
            p2c[i] = pc;
            int r2 = pc / 18, c2 = pc - r2 * 18;
            pxb[i] = r2 * 20 + c2;
            int gy1 = y0 - 1 + r2, gx1 = x0 - 1 + c2;
            inb[i] = (gy1 >= 0 && gy1 < HW && gx1 >= 0 && gx1 < HW);
        }
    }
    float4v acc1[3][4];
#pragma unroll
    for (int i = 0; i < 3; ++i)
#pragma unroll
        for (int mt = 0; mt < 4; ++mt) acc1[i][mt] = (float4v){0.f, 0.f, 0.f, 0.f};

#pragma unroll
    for (int tap = 0; tap < 9; ++tap) {
        const int ky = tap / 3, kx = tap - (tap / 3) * 3;
        const int po = ky * 20 + kx;
        short8 A[4];
#pragma unroll
        for (int mt = 0; mt < 4; ++mt) A[mt] = Apre[mt];
        if (tap < 8) {
#pragma unroll
            for (int mt = 0; mt < 4; ++mt)
                Apre[mt] = *(const short8*)(wb + (tap + 1) * 2048 + (mt * 16 + l15) * 32 + lg * 8);
        }
#pragma unroll
        for (int i = 0; i < 3; ++i) {
            int g = wave + i * 8;
            if (g < 21) {
                int px20 = pxb[i] + po;
                short8 Bf = *(const short8*)((const char*)b0s + px20 * 64 +
                                             ((lg ^ ((px20 >> 1) & 3)) << 4));
#pragma unroll
                for (int mt = 0; mt < 4; ++mt)
                    acc1[i][mt] = __builtin_amdgcn_mfma_f32_16x16x32_bf16(A[mt], Bf, acc1[i][mt], 0, 0, 0);
            }
        }
    }

    // ---- conv2 in-register: B-frag[kc] = bf16(acc1[2kc], acc1[2kc+1]); D[m=tap][n=px] ----
#pragma unroll
    for (int i = 0; i < 3; ++i) {
        int g = wave + i * 8;
        if (g < 21) {
            int pc = p2c[i];
            float4v acc2 = (float4v){0.f, 0.f, 0.f, 0.f};
#pragma unroll
            for (int kc = 0; kc < 2; ++kc) {
                uint4 dv;
                dv.x = pack2rnd(acc1[i][kc * 2][0],     acc1[i][kc * 2][1]);
                dv.y = pack2rnd(acc1[i][kc * 2][2],     acc1[i][kc * 2][3]);
                dv.z = pack2rnd(acc1[i][kc * 2 + 1][0], acc1[i][kc * 2 + 1][1]);
                dv.w = pack2rnd(acc1[i][kc * 2 + 1][2], acc1[i][kc * 2 + 1][3]);
                if (!inb[i]) { dv.x = 0; dv.y = 0; dv.z = 0; dv.w = 0; }
                short8 Bf = __builtin_bit_cast(short8, dv);
                acc2 = __builtin_amdgcn_mfma_f32_16x16x32_bf16(A2[kc], Bf, acc2, 0, 0, 0);
            }
            if (lg < 2) {
#pragma unroll
                for (int u = 0; u < 4; ++u) pbuf[pc * 13 + lg * 4 + u] = acc2[u];
            } else if (lg == 2) {
                pbuf[pc * 13 + 8] = acc2[0];
            }
        }
    }
    __syncthreads();   // 3

    // ---- reduction: out(r,c) = sum_tap pbuf[(r+ky)*18 + (c+kx)][tap] ----
    if (t < 256) {
        int r = t >> 4, c = t & 15;
        float o = 0.f;
#pragma unroll
        for (int ky = 0; ky < 3; ++ky)
#pragma unroll
            for (int kx = 0; kx < 3; ++kx)
                o += pbuf[((r + ky) * 18 + (c + kx)) * 13 + (ky * 3 + kx)];
        out[(size_t)b * HWHW + (y0 + r) * HW + (x0 + c)] = o;
    }
}

extern "C" void kernel_launch(void* const* d_in, const int* in_sizes, int n_in,
                              void* d_out, int out_size, void* d_ws, size_t ws_size,
                              hipStream_t stream)
{
    const float* x_meta = (const float*)d_in[0];
    const float* x      = (const float*)d_in[1];
    const float* w0     = (const float*)d_in[2];
    const float* b0     = (const float*)d_in[3];
    const float* w1     = (const float*)d_in[4];
    const float* b1     = (const float*)d_in[5];
    const float* w2     = (const float*)d_in[6];
    const float* b2     = (const float*)d_in[7];
    float* out = (float*)d_out;

    char* ws = (char*)d_ws;
    float* h1 = (float*)ws;                                                // @0       32768 B
    float* wc0 = (float*)(ws + 32768);                                     // @32768   18432 B
    unsigned short* wc1 = (unsigned short*)(ws + 51200);                   // @51200   589824 B
    unsigned short* wc2 = (unsigned short*)(ws + 641024);                  // @641024  18432 B

    mlp_kernel<<<dim3(2, 16), 256, 0, stream>>>(x_meta, w0, b0, w1, b1, h1);
    flat_kernel<<<302, 256, 0, stream>>>(h1, w2, b2, wc0, wc1, wc2);
    fused_conv_kernel<<<dim3(256, 16), 512, 0, stream>>>(x, wc0, wc1, wc2, out);
}